// Round 22
// baseline (32.737 us; speedup 1.0000x reference)
//
#include <hip/hip_runtime.h>
#include <hip/hip_fp16.h>
#include <float.h>

constexpr int KMAX  = 11;    // KS_MAX
constexpr int SEQ   = 512;   // SEQ_LEN
constexpr int NB    = 64;    // BATCH
constexpr int NBB   = 8;     // batches per main block (8 groups)
constexpr int NGRP  = NB / NBB;
constexpr int KPB   = 4;     // kernels per block = 1 per wave
constexpr int MSTR  = 32;    // meta ints per k: [0]=nj [1..11]=c [12..22]=w2bits
constexpr int SBASE = 512;   // fixed window: slot = s + 512
constexpr int WSLOT = 1600;  // s in [-512, 1088)

__device__ __forceinline__ unsigned h2b(__half2 h) { unsigned u; __builtin_memcpy(&u, &h, 4); return u; }
__device__ __forceinline__ __half2  b2h(unsigned u) { __half2 h; __builtin_memcpy(&h, &u, 4); return h; }

// ROCm 7.2 has no __hmax2/__hmin2 — use VOP3P directly.
__device__ __forceinline__ unsigned pkmax(unsigned a, unsigned b) {
    unsigned d; asm("v_pk_max_f16 %0, %1, %2" : "=v"(d) : "v"(a), "v"(b)); return d;
}
__device__ __forceinline__ unsigned pkadd(unsigned a, unsigned b) { return h2b(__hadd2(b2h(a), b2h(b))); }
__device__ __forceinline__ __half2 h2max(__half2 a, __half2 b) { return b2h(pkmax(h2b(a), h2b(b))); }
// fused (a*b+c) clamped to [0,1] — the whole count update in one VOP3P
__device__ __forceinline__ unsigned pkfma_clamp(unsigned a, unsigned b, unsigned c) {
    unsigned d; asm("v_pk_fma_f16 %0, %1, %2, %3 clamp" : "=v"(d) : "v"(a), "v"(b), "v"(c)); return d;
}

template<int CTRL>
__device__ __forceinline__ unsigned dppmov(unsigned old, unsigned v) {
    return (unsigned)__builtin_amdgcn_update_dpp((int)old, (int)v, CTRL, 0xF, 0xF, false);
}
constexpr unsigned NEGINF2 = 0xFC00FC00u;   // -inf | -inf (f16 pair)

__device__ __forceinline__ unsigned dpp_redmax(unsigned x) {
    x = pkmax(x, dppmov<0xB1 >(NEGINF2, x));  // quad_perm xor1
    x = pkmax(x, dppmov<0x4E >(NEGINF2, x));  // quad_perm xor2
    x = pkmax(x, dppmov<0x141>(NEGINF2, x));  // row_half_mirror
    x = pkmax(x, dppmov<0x140>(NEGINF2, x));  // row_mirror
    x = pkmax(x, dppmov<0x142>(NEGINF2, x));  // row_bcast15
    x = pkmax(x, dppmov<0x143>(NEGINF2, x));  // row_bcast31
    return x;                                  // lane 63 valid
}
__device__ __forceinline__ unsigned dpp_redadd(unsigned x) {
    x = pkadd(x, dppmov<0xB1 >(0u, x));
    x = pkadd(x, dppmov<0x4E >(0u, x));
    x = pkadd(x, dppmov<0x141>(0u, x));
    x = pkadd(x, dppmov<0x140>(0u, x));
    x = pkadd(x, dppmov<0x142>(0u, x));
    x = pkadd(x, dppmov<0x143>(0u, x));
    return x;                                  // lane 63 valid
}

// ======================= prep kernel (identical to R21) =======================
__global__ __launch_bounds__(256)
void prep_kernel(const float* __restrict__ x, const float* __restrict__ w,
                 const int* __restrict__ idx, int* __restrict__ meta,
                 unsigned short* __restrict__ xt, int K, int maxL)
{
    const int tid = threadIdx.x;
    if ((int)blockIdx.x >= K) {
        const int j  = ((int)blockIdx.x - K) * 256 + tid;   // 0..8191
        const int b  = j >> 7, s4 = j & 127;
        const float4 v = reinterpret_cast<const float4*>(x)[b * (SEQ / 4) + s4];
        const int g = b >> 3, bl = b & 7;
        unsigned short* dst = xt + ((size_t)g * SEQ + s4 * 4) * NBB + bl;
        __half h;
        h = __float2half_rn(v.x); __builtin_memcpy(&dst[0 * NBB], &h, 2);
        h = __float2half_rn(v.y); __builtin_memcpy(&dst[1 * NBB], &h, 2);
        h = __float2half_rn(v.z); __builtin_memcpy(&dst[2 * NBB], &h, 2);
        h = __float2half_rn(v.w); __builtin_memcpy(&dst[3 * NBB], &h, 2);
        return;
    }

    if (tid >= 64) return;               // wave 0 only; no barriers below
    const int k = blockIdx.x, lane = tid;
    const int* idk = idx + (size_t)k * KMAX * (size_t)maxL;

    // affine derivation: c_j = c0 + j*d; probe rows 0,1 at t in [0,64) and [448,512)
    const int t0 = min(lane, maxL - 1);
    const int t7 = min(448 + lane, maxL - 1);
    const int v00 = idk[t0];
    const int v07 = idk[t7];
    const int v10 = idk[maxL + t0];
    const int v17 = idk[maxL + t7];
    const float w_l = (lane < KMAX) ? w[(size_t)k * KMAX + lane] : 0.f;

    int c0 = 0, c1 = 0;
    bool ok0 = false, ok1 = false;
    {
        unsigned long long m = __ballot((v00 > 0) && (v00 < SEQ - 1));
        if (m) { const int fl = __builtin_ctzll(m); c0 = __shfl(v00, fl) - min(fl, maxL - 1); ok0 = true; }
        else {
            m = __ballot((v07 > 0) && (v07 < SEQ - 1));
            if (m) { const int fl = __builtin_ctzll(m); c0 = __shfl(v07, fl) - min(448 + fl, maxL - 1); ok0 = true; }
        }
    }
    {
        unsigned long long m = __ballot((v10 > 0) && (v10 < SEQ - 1));
        if (m) { const int fl = __builtin_ctzll(m); c1 = __shfl(v10, fl) - min(fl, maxL - 1); ok1 = true; }
        else {
            m = __ballot((v17 > 0) && (v17 < SEQ - 1));
            if (m) { const int fl = __builtin_ctzll(m); c1 = __shfl(v17, fl) - min(448 + fl, maxL - 1); ok1 = true; }
        }
    }
    if (!ok0) {
        for (int base = 0; base < maxL; base += 64) {
            const int t = base + lane;
            const int v = (t < maxL) ? idk[t] : 0;
            const unsigned long long m = __ballot((v > 0) && (v < SEQ - 1));
            if (m) { const int fl = __builtin_ctzll(m); c0 = __shfl(v, fl) - (base + fl); break; }
        }
    }
    if (!ok1) {
        for (int base = 0; base < maxL; base += 64) {
            const int t = base + lane;
            const int v = (t < maxL) ? idk[maxL + t] : 0;
            const unsigned long long m = __ballot((v > 0) && (v < SEQ - 1));
            if (m) { const int fl = __builtin_ctzll(m); c1 = __shfl(v, fl) - (base + fl); break; }
        }
    }
    const int d = c1 - c0;               // c_j = c0 + j*d (affine in j)

    if (lane == 0) {
        int* mk = meta + (size_t)k * MSTR;
        int n = 0;
        for (int j = 0; j < KMAX; ++j) {
            const float wj = __int_as_float(__builtin_amdgcn_readlane(__float_as_int(w_l), j));
            if (wj != 0.0f) {
                mk[1 + n] = c0 + j * d;
                __half hw = __float2half_rn(wj);
                unsigned short ub; __builtin_memcpy(&ub, &hw, 2);
                mk[12 + n] = (unsigned)ub | ((unsigned)ub << 16);
                ++n;
            }
        }
        for (int jj = n; jj < KMAX; ++jj) { mk[1 + jj] = 0; mk[12 + jj] = 0; }
        mk[0] = n;
    }
}

// ======================= sort kernel: descending-lout counting sort =======================
// One block. perm is pure scheduling: outputs are indexed by k, so results are
// bitwise-identical for any intra-bucket order.
__global__ __launch_bounds__(256)
void sortk_kernel(const int* __restrict__ l_out, int* __restrict__ perm, int K)
{
    __shared__ int hist[16], base[16];
    const int tid = threadIdx.x;
    if (tid < 16) hist[tid] = 0;
    __syncthreads();
    for (int k = tid; k < K; k += 256)
        atomicAdd(&hist[15 - min(15, l_out[k] >> 6)], 1);   // bucket 0 = longest
    __syncthreads();
    if (tid == 0) {
        int run = 0;
        for (int b = 0; b < 16; ++b) { base[b] = run; run += hist[b]; }
    }
    __syncthreads();
    for (int k = tid; k < K; k += 256)
        perm[atomicAdd(&base[15 - min(15, l_out[k] >> 6)], 1)] = k;
}

// ======================= main kernel (R21 body; k comes from perm) =======================
template<int NJ>
__device__ __forceinline__ void conv_wave(
    const char* __restrict__ xsc, int mrow, int lout, int lane, unsigned ctermb,
    unsigned (&um)[4], unsigned (&uc)[4])
{
    const __half2 zero2 = __float2half2_rn(0.f);
    const __half2 nbig2 = __float2half2_rn(-65504.f);
    const unsigned C4b  = 0x74007400u;   // f16 pair {2^14, 2^14}

    int addr[NJ]; __half2 wr[NJ];
#pragma unroll
    for (int j = 0; j < NJ; ++j) {
        const int c = __builtin_amdgcn_readlane(mrow, 1 + j);
        wr[j]   = b2h((unsigned)__builtin_amdgcn_readlane(mrow, 12 + j));
        addr[j] = (lane + c + SBASE) * 16;
    }
    __half2 mx2[4], ct2[4];
#pragma unroll
    for (int m = 0; m < 4; ++m) { mx2[m] = nbig2; ct2[m] = zero2; }

    const int nfull = lout >> 6;
    const int ng4   = nfull >> 2;

    for (int g = 0; g < ng4; ++g) {       // groups of 4 full chunks, immediate offsets
#pragma unroll
        for (int u = 0; u < 4; ++u) {
            uint4 d[NJ];
#pragma unroll
            for (int j = 0; j < NJ; ++j)
                d[j] = *reinterpret_cast<const uint4*>(xsc + addr[j] + u * 1024);
            __half2 a[4] = {zero2, zero2, zero2, zero2};
#pragma unroll
            for (int j = 0; j < NJ; ++j) {
                a[0] = __hfma2(wr[j], b2h(d[j].x), a[0]);
                a[1] = __hfma2(wr[j], b2h(d[j].y), a[1]);
                a[2] = __hfma2(wr[j], b2h(d[j].z), a[2]);
                a[3] = __hfma2(wr[j], b2h(d[j].w), a[3]);
            }
#pragma unroll
            for (int m = 0; m < 4; ++m) {
                mx2[m] = h2max(mx2[m], a[m]);
                ct2[m] = b2h(pkadd(h2b(ct2[m]), pkfma_clamp(h2b(a[m]), C4b, ctermb)));
            }
        }
#pragma unroll
        for (int j = 0; j < NJ; ++j) addr[j] += 4096;
    }
    for (int u = 0; u < (nfull & 3); ++u) {   // leftover full chunks
        uint4 d[NJ];
#pragma unroll
        for (int j = 0; j < NJ; ++j)
            d[j] = *reinterpret_cast<const uint4*>(xsc + addr[j]);
        __half2 a[4] = {zero2, zero2, zero2, zero2};
#pragma unroll
        for (int j = 0; j < NJ; ++j) {
            a[0] = __hfma2(wr[j], b2h(d[j].x), a[0]);
            a[1] = __hfma2(wr[j], b2h(d[j].y), a[1]);
            a[2] = __hfma2(wr[j], b2h(d[j].z), a[2]);
            a[3] = __hfma2(wr[j], b2h(d[j].w), a[3]);
        }
#pragma unroll
        for (int m = 0; m < 4; ++m) {
            mx2[m] = h2max(mx2[m], a[m]);
            ct2[m] = b2h(pkadd(h2b(ct2[m]), pkfma_clamp(h2b(a[m]), C4b, ctermb)));
        }
#pragma unroll
        for (int j = 0; j < NJ; ++j) addr[j] += 1024;
    }
    const int rem = lout & 63;
    if (rem) {                                 // straddle chunk, lane-masked
        uint4 d[NJ];
#pragma unroll
        for (int j = 0; j < NJ; ++j)
            d[j] = *reinterpret_cast<const uint4*>(xsc + addr[j]);
        __half2 a[4] = {zero2, zero2, zero2, zero2};
#pragma unroll
        for (int j = 0; j < NJ; ++j) {
            a[0] = __hfma2(wr[j], b2h(d[j].x), a[0]);
            a[1] = __hfma2(wr[j], b2h(d[j].y), a[1]);
            a[2] = __hfma2(wr[j], b2h(d[j].z), a[2]);
            a[3] = __hfma2(wr[j], b2h(d[j].w), a[3]);
        }
        const bool tm = lane < rem;
#pragma unroll
        for (int m = 0; m < 4; ++m) {
            a[m] = tm ? a[m] : nbig2;          // -65504*2^14 -> -inf -> clamp -> 0
            mx2[m] = h2max(mx2[m], a[m]);
            ct2[m] = b2h(pkadd(h2b(ct2[m]), pkfma_clamp(h2b(a[m]), C4b, ctermb)));
        }
    }

#pragma unroll
    for (int m = 0; m < 4; ++m) {
        um[m] = dpp_redmax(h2b(mx2[m]));
        uc[m] = dpp_redadd(h2b(ct2[m]));
    }
}

__global__ __launch_bounds__(256, 4)
void rocket_main(const unsigned short* __restrict__ xt, const int* __restrict__ meta,
                 const float* __restrict__ bias, const int* __restrict__ l_out,
                 const int* __restrict__ perm, float* __restrict__ out, int K)
{
    __shared__ __align__(16) unsigned xs_u[WSLOT * 4];   // 25600 B fixed window

    const int ibase = (int)blockIdx.x * KPB;
    const int grp   = blockIdx.y;
    const int tid   = threadIdx.x;
    const int wave  = tid >> 6, lane = tid & 63;

    // ---- hoisted per-wave loads: issued BEFORE staging, consumed after barrier ----
    const int i  = ibase + wave;
    const int ic = min(i, K - 1);                        // safe addr for i >= K
    const int k  = perm[ic];                             // LPT + similar-lout grouping
    const int   mrow_v = meta[(size_t)k * MSTR + (lane & 31)];
    const int   lout_v = l_out[k];
    const float bias_v = bias[k];

    // ---- stage fixed window (zeros outside s in [0,512)); conflict-free b128 ----
    float4* xs4 = reinterpret_cast<float4*>(xs_u);
    const float4* src = reinterpret_cast<const float4*>(xt + (size_t)grp * SEQ * NBB);
    const float4 z4 = make_float4(0.f, 0.f, 0.f, 0.f);
    for (int t = tid; t < WSLOT; t += 256) {
        const int s = t - SBASE;
        xs4[t] = ((unsigned)s < (unsigned)SEQ) ? src[s] : z4;
    }
    __syncthreads();

    if (i >= K) return;

    const int nj    = __builtin_amdgcn_readlane(mrow_v, 0);
    const int lout  = __builtin_amdgcn_readfirstlane(lout_v);
    const float biasf = __int_as_float(__builtin_amdgcn_readfirstlane(__float_as_int(bias_v)));
    const unsigned ctermb = h2b(__float2half2_rn(biasf * 16384.f));

    unsigned um[4], uc[4];
    const char* xsc = reinterpret_cast<const char*>(xs_u);
    if (nj <= 7)      conv_wave<7 >(xsc, mrow_v, lout, lane, ctermb, um, uc);
    else if (nj <= 9) conv_wave<9 >(xsc, mrow_v, lout, lane, ctermb, um, uc);
    else              conv_wave<11>(xsc, mrow_v, lout, lane, ctermb, um, uc);

    // ---- lane 63 finalizes: 8 batches x {max, ppv} ----
    if (lane == 63) {
        const float loutf = (float)lout;
#pragma unroll
        for (int m = 0; m < 4; ++m) {
            const __half2 hm = b2h(um[m]);
            const __half2 hc = b2h(uc[m]);
            float* o0 = out + (size_t)(grp * NBB + 2 * m) * (2 * K) + 2 * k;
            o0[0] = __low2float(hm) + biasf;           // deferred bias
            o0[1] = __low2float(hc) / loutf;
            float* o1 = o0 + 2 * K;
            o1[0] = __high2float(hm) + biasf;
            o1[1] = __high2float(hc) / loutf;
        }
    }
}

// ======================= launch =======================
extern "C" void kernel_launch(void* const* d_in, const int* in_sizes, int n_in,
                              void* d_out, int out_size, void* d_ws, size_t ws_size,
                              hipStream_t stream)
{
    const float* x    = (const float*)d_in[0];
    const float* w    = (const float*)d_in[1];
    const float* bias = (const float*)d_in[2];
    const int*   idx  = (const int*)d_in[3];
    // d_in[4] = valid (unused: validity derived exactly from the idx ramp)
    const int*   lout = (const int*)d_in[5];
    float* out = (float*)d_out;

    const int K    = in_sizes[2];               // N_KERNELS
    const int maxL = in_sizes[3] / (K * KMAX);  // idx = [K][KMAX][maxL]

    // workspace: meta (K*32 ints) | xt16 (NB*SEQ f16) | perm (K ints)
    char* wsp = (char*)d_ws;
    int* meta = (int*)wsp;
    size_t o1 = ((size_t)K * MSTR * sizeof(int) + 255) & ~(size_t)255;
    unsigned short* xt = (unsigned short*)(wsp + o1);
    size_t o2 = o1 + (((size_t)NB * SEQ * 2 + 255) & ~(size_t)255);
    int* perm = (int*)(wsp + o2);

    prep_kernel<<<K + 32, 256, 0, stream>>>(x, w, idx, meta, xt, K, maxL);
    sortk_kernel<<<1, 256, 0, stream>>>(lout, perm, K);
    rocket_main<<<dim3((K + KPB - 1) / KPB, NGRP), 256, 0, stream>>>(xt, meta, bias, lout, perm, out, K);
}